// Round 6
// baseline (300.605 us; speedup 1.0000x reference)
//
#include <hip/hip_runtime.h>
#include <hip/hip_fp16.h>
#include <math.h>

#define N_NODES 100000
#define N_EDGES 3200000
#define F_IN    128
#define F_HID   32
#define F_OUT   40
#define NBINS   ((N_NODES + 255) >> 8)   // 391 coarse bins of 256 nodes
#define EPB     2048                     // edges per block in partition pass A

// ---------------------------------------------------------------------------
// GEMM1: h1h[N,32] = fp16(x[N,128] @ W1[128,32])
// ---------------------------------------------------------------------------
__global__ __launch_bounds__(256) void gemm1_kernel(const float* __restrict__ x,
                                                    const float* __restrict__ W,
                                                    __half* __restrict__ h1h) {
    __shared__ float Ws[F_IN * F_HID];     // 16 KB
    __shared__ float Xs[32][F_IN + 4];
    const int tid  = threadIdx.x;
    const int row0 = blockIdx.x * 32;

    for (int i = tid; i < (F_IN * F_HID) / 4; i += 256)
        ((float4*)Ws)[i] = ((const float4*)W)[i];

    for (int i = tid; i < 1024; i += 256) {
        int r = i >> 5;
        int c = i & 31;
        ((float4*)&Xs[r][0])[c] = ((const float4*)x)[(size_t)(row0 + r) * (F_IN / 4) + c];
    }
    __syncthreads();

    const int r  = tid >> 3;
    const int c0 = (tid & 7) * 4;
    float a0 = 0.f, a1 = 0.f, a2 = 0.f, a3 = 0.f;
    for (int k = 0; k < F_IN; ++k) {
        const float xv = Xs[r][k];
        const float* wrow = &Ws[k * F_HID + c0];
        a0 += xv * wrow[0];
        a1 += xv * wrow[1];
        a2 += xv * wrow[2];
        a3 += xv * wrow[3];
    }
    const int row = row0 + r;   // grid exact: 3125*32 == N_NODES
    __half2* o = (__half2*)(h1h + (size_t)row * F_HID + c0);
    o[0] = __floats2half2_rn(a0, a1);
    o[1] = __floats2half2_rn(a2, a3);
}

// ---------------------------------------------------------------------------
// Coarse-bin histogram (391 bins), LDS-aggregated.
// ---------------------------------------------------------------------------
__global__ __launch_bounds__(256) void binhist_kernel(const int* __restrict__ ei,
                                                      int* __restrict__ bincnt) {
    __shared__ int lc[NBINS];
    for (int i = threadIdx.x; i < NBINS; i += 256) lc[i] = 0;
    __syncthreads();
    const int stride = gridDim.x * 256;
    for (int e = blockIdx.x * 256 + threadIdx.x; e < N_EDGES; e += stride)
        atomicAdd(&lc[ei[N_EDGES + e] >> 8], 1);
    __syncthreads();
    for (int i = threadIdx.x; i < NBINS; i += 256)
        if (lc[i]) atomicAdd(&bincnt[i], lc[i]);
}

// ---------------------------------------------------------------------------
// Scan over 391 bin counts -> binbase[0..NBINS], cursor, offs[N]=E.
// ---------------------------------------------------------------------------
__global__ __launch_bounds__(512) void binscan_kernel(const int* __restrict__ bincnt,
                                                      int* __restrict__ binbase,
                                                      int* __restrict__ cursor,
                                                      int* __restrict__ offs) {
    __shared__ int s[512];
    const int t = threadIdx.x;
    const int v = (t < NBINS) ? bincnt[t] : 0;
    s[t] = v;
    __syncthreads();
    for (int off = 1; off < 512; off <<= 1) {
        int u = (t >= off) ? s[t - off] : 0;
        __syncthreads();
        s[t] += u;
        __syncthreads();
    }
    const int excl = s[t] - v;
    if (t <= NBINS) binbase[t] = excl;
    if (t < NBINS)  cursor[t]  = excl;
    if (t == 0)     offs[N_NODES] = N_EDGES;
}

// ---------------------------------------------------------------------------
// Pass A: partition edges into coarse bins. Per-WAVE sub-histograms and
// cursors (4 private copies) to cut LDS atomic contention; per-wave bases
// derived from one global atomic per (block, bin). Staged entry:
//   .x = src(17b) | dst_low8 << 17, .y = weight fp32 bits.
// ---------------------------------------------------------------------------
__global__ __launch_bounds__(256) void partA_kernel(const int* __restrict__ ei,
                                                    const float* __restrict__ ew,
                                                    int* __restrict__ cursor,
                                                    int2* __restrict__ stg) {
    __shared__ int lh[4 * NBINS];          // per-wave hist, then per-wave cursor
    const int tid = threadIdx.x;
    const int wv  = tid >> 6;
    const int e0  = blockIdx.x * EPB;

    for (int i = tid; i < 4 * NBINS; i += 256) lh[i] = 0;
    __syncthreads();

    // count (each wave into its private copy)
    for (int k = tid; k < EPB; k += 256) {
        const int e = e0 + k;
        if (e < N_EDGES) atomicAdd(&lh[wv * NBINS + (ei[N_EDGES + e] >> 8)], 1);
    }
    __syncthreads();

    // reserve one global range per bin; carve per-wave exclusive bases
    for (int b = tid; b < NBINS; b += 256) {
        const int c0 = lh[b];
        const int c1 = lh[NBINS + b];
        const int c2 = lh[2 * NBINS + b];
        const int c3 = lh[3 * NBINS + b];
        const int tot = c0 + c1 + c2 + c3;
        const int base = tot ? atomicAdd(&cursor[b], tot) : 0;
        lh[b]             = base;
        lh[NBINS + b]     = base + c0;
        lh[2 * NBINS + b] = base + c0 + c1;
        lh[3 * NBINS + b] = base + c0 + c1 + c2;
    }
    __syncthreads();

    // place with per-wave cursors
    for (int k = tid; k < EPB; k += 256) {
        const int e = e0 + k;
        if (e < N_EDGES) {
            const int src = ei[e];
            const int dst = ei[N_EDGES + e];
            const int pos = atomicAdd(&lh[wv * NBINS + (dst >> 8)], 1);
            stg[pos] = make_int2(src | ((dst & 255) << 17),
                                 __float_as_int(ew[e]));
        }
    }
}

// ---------------------------------------------------------------------------
// Pass B: one block per bin. Per-wave per-node counts in LDS, block-level
// scan writes offs, per-wave cursors for placement. Packed 4B entries:
//   src(17b) | fp16bits(w) << 17   (w in [0,1] -> half bits < 2^15).
// ---------------------------------------------------------------------------
__global__ __launch_bounds__(256) void partB_kernel(const int* __restrict__ binbase,
                                                    const int2* __restrict__ stg,
                                                    int* __restrict__ offs,
                                                    int* __restrict__ bkt) {
    __shared__ int lc[4][256];
    __shared__ int lsc[256];
    const int tid   = threadIdx.x;
    const int wv    = tid >> 6;
    const int b     = blockIdx.x;
    const int start = binbase[b];
    const int end   = binbase[b + 1];

    lc[0][tid] = 0; lc[1][tid] = 0; lc[2][tid] = 0; lc[3][tid] = 0;
    __syncthreads();
    for (int j = start + tid; j < end; j += 256)
        atomicAdd(&lc[wv][(stg[j].x >> 17) & 255], 1);
    __syncthreads();

    const int c0 = lc[0][tid], c1 = lc[1][tid], c2 = lc[2][tid], c3 = lc[3][tid];
    const int v = c0 + c1 + c2 + c3;
    lsc[tid] = v;
    __syncthreads();
    for (int off = 1; off < 256; off <<= 1) {
        int u = (tid >= off) ? lsc[tid - off] : 0;
        __syncthreads();
        lsc[tid] += u;
        __syncthreads();
    }
    const int base = start + (lsc[tid] - v);
    const int node = (b << 8) + tid;
    if (node < N_NODES) offs[node] = base;
    lc[0][tid] = base;
    lc[1][tid] = base + c0;
    lc[2][tid] = base + c0 + c1;
    lc[3][tid] = base + c0 + c1 + c2;
    __syncthreads();

    for (int j = start + tid; j < end; j += 256) {
        const int2 p = stg[j];
        const int dlow = (p.x >> 17) & 255;
        const unsigned hb = __half_as_ushort(__float2half(__int_as_float(p.y)));
        const int pos = atomicAdd(&lc[wv][dlow], 1);
        bkt[pos] = (p.x & 0x1FFFF) | ((int)hb << 17);
    }
}

// ---------------------------------------------------------------------------
// Shared gather core: 8 edge-groups x 8 lanes; each lane holds an 8B (4-feat)
// row fragment; 2-deep unroll = 16 edges in flight per wave.
// ---------------------------------------------------------------------------
#define GATHER_EDGE(P, A0, A1, A2, A3)                                          \
    {                                                                           \
        const float wgt = __half2float(__ushort_as_half(                        \
            (unsigned short)((unsigned)(P) >> 17)));                            \
        const uint2 rv = *(const uint2*)(tbl + (((unsigned)((P) & 0x1FFFF)) << 6) + sub8); \
        float2 v;                                                               \
        v = __half22float2(*(const __half2*)&rv.x);                             \
        A0 += v.x * wgt; A1 += v.y * wgt;                                       \
        v = __half22float2(*(const __half2*)&rv.y);                             \
        A2 += v.x * wgt; A3 += v.y * wgt;                                       \
    }

// ---------------------------------------------------------------------------
// Gather 1 + bias1 + ReLU: rh[n] = fp16(relu(sum_e w_e * h1h[src_e] + b1))
// ---------------------------------------------------------------------------
__global__ __launch_bounds__(256) void gather1_kernel(const int* __restrict__ offs,
                                                      const int* __restrict__ bkt,
                                                      const __half* __restrict__ h1h,
                                                      const float* __restrict__ b1,
                                                      __half* __restrict__ rh) {
    const int wave = threadIdx.x >> 6, lane = threadIdx.x & 63;
    const int node = blockIdx.x * 4 + wave;          // grid exact: 25000*4
    const int g    = lane >> 3;
    const int sub  = lane & 7;
    const unsigned sub8 = sub * 8;
    const char* tbl = (const char*)h1h;

    int j = offs[node] + g;
    const int jend = offs[node + 1];
    float a0 = 0.f, a1 = 0.f, a2 = 0.f, a3 = 0.f;
    float c0 = 0.f, c1 = 0.f, c2 = 0.f, c3 = 0.f;
    for (; j + 8 < jend; j += 16) {
        const int p0 = bkt[j];
        const int p1 = bkt[j + 8];
        GATHER_EDGE(p0, a0, a1, a2, a3);
        GATHER_EDGE(p1, c0, c1, c2, c3);
    }
    if (j < jend) {
        const int p = bkt[j];
        GATHER_EDGE(p, a0, a1, a2, a3);
    }
    a0 += c0; a1 += c1; a2 += c2; a3 += c3;
    #pragma unroll
    for (int off = 8; off < 64; off <<= 1) {
        a0 += __shfl_xor(a0, off);
        a1 += __shfl_xor(a1, off);
        a2 += __shfl_xor(a2, off);
        a3 += __shfl_xor(a3, off);
    }
    if (g == 0) {
        const float4 bb = ((const float4*)b1)[sub];
        a0 = fmaxf(a0 + bb.x, 0.f);
        a1 = fmaxf(a1 + bb.y, 0.f);
        a2 = fmaxf(a2 + bb.z, 0.f);
        a3 = fmaxf(a3 + bb.w, 0.f);
        uint2 o;
        *(__half2*)&o.x = __floats2half2_rn(a0, a1);
        *(__half2*)&o.y = __floats2half2_rn(a2, a3);
        *(uint2*)((char*)rh + (size_t)node * 64 + sub8) = o;
    }
}

// ---------------------------------------------------------------------------
// Gather 2 + GEMM2 + bias2 + log-softmax, all fused. One wave per node.
// ---------------------------------------------------------------------------
__global__ __launch_bounds__(256) void gather2_lsm_kernel(const int* __restrict__ offs,
                                                          const int* __restrict__ bkt,
                                                          const __half* __restrict__ rh,
                                                          const float* __restrict__ W2,
                                                          const float* __restrict__ b2,
                                                          float* __restrict__ out) {
    __shared__ float W2s[F_HID * F_OUT];   // 5 KB
    __shared__ float rb[4][F_HID];
    const int tid = threadIdx.x;
    for (int i = tid; i < F_HID * F_OUT; i += 256) W2s[i] = W2[i];

    const int wave = tid >> 6, lane = tid & 63;
    const int node = blockIdx.x * 4 + wave;          // grid exact
    const int g    = lane >> 3;
    const int sub  = lane & 7;
    const unsigned sub8 = sub * 8;
    const char* tbl = (const char*)rh;

    int j = offs[node] + g;
    const int jend = offs[node + 1];
    float a0 = 0.f, a1 = 0.f, a2 = 0.f, a3 = 0.f;
    float c0 = 0.f, c1 = 0.f, c2 = 0.f, c3 = 0.f;
    for (; j + 8 < jend; j += 16) {
        const int p0 = bkt[j];
        const int p1 = bkt[j + 8];
        GATHER_EDGE(p0, a0, a1, a2, a3);
        GATHER_EDGE(p1, c0, c1, c2, c3);
    }
    if (j < jend) {
        const int p = bkt[j];
        GATHER_EDGE(p, a0, a1, a2, a3);
    }
    a0 += c0; a1 += c1; a2 += c2; a3 += c3;
    #pragma unroll
    for (int off = 8; off < 64; off <<= 1) {
        a0 += __shfl_xor(a0, off);
        a1 += __shfl_xor(a1, off);
        a2 += __shfl_xor(a2, off);
        a3 += __shfl_xor(a3, off);
    }
    if (g == 0)
        ((float4*)&rb[wave][0])[sub] = make_float4(a0, a1, a2, a3);
    __syncthreads();

    float val = -INFINITY;
    if (lane < F_OUT) {
        float acc = b2[lane];
        #pragma unroll
        for (int k = 0; k < F_HID; ++k)
            acc += rb[wave][k] * W2s[k * F_OUT + lane];
        val = acc;
    }
    float m = val;
    for (int off = 32; off; off >>= 1) m = fmaxf(m, __shfl_xor(m, off));
    float ex = (lane < F_OUT) ? expf(val - m) : 0.f;
    for (int off = 32; off; off >>= 1) ex += __shfl_xor(ex, off);
    if (lane < F_OUT) out[(size_t)node * F_OUT + lane] = val - m - logf(ex);
}

// ---------------------------------------------------------------------------
extern "C" void kernel_launch(void* const* d_in, const int* in_sizes, int n_in,
                              void* d_out, int out_size, void* d_ws, size_t ws_size,
                              hipStream_t stream) {
    const float* x  = (const float*)d_in[0];
    const int*   ei = (const int*)d_in[1];    // [2, E] int32: row 0 = src, row 1 = dst
    const float* ew = (const float*)d_in[2];
    const float* W1 = (const float*)d_in[3];
    const float* b1 = (const float*)d_in[4];
    const float* W2 = (const float*)d_in[5];
    const float* b2 = (const float*)d_in[6];
    float* out = (float*)d_out;

    // Workspace layout (16B-aligned):
    //   bincnt  : NBINS ints
    //   binbase : NBINS+1 ints
    //   cursor  : NBINS ints
    //   offs    : N+1 ints          0.4 MB
    //   bkt     : E ints           12.8 MB
    //   union   : stg[E] int2 (25.6 MB, build only)  /  h1h + rh fp16 (12.8 MB)
    char* p = (char*)d_ws;
    size_t off = 0;
    auto alloc = [&](size_t bytes) {
        char* r = p + off;
        off += (bytes + 15) & ~(size_t)15;
        return r;
    };
    int*   bincnt  = (int*)  alloc((size_t)NBINS * 4);
    int*   binbase = (int*)  alloc((size_t)(NBINS + 1) * 4);
    int*   cursor  = (int*)  alloc((size_t)NBINS * 4);
    int*   offs    = (int*)  alloc((size_t)(N_NODES + 1) * 4);
    int*   bkt     = (int*)  alloc((size_t)N_EDGES * 4);
    char*  uni     = (char*) alloc((size_t)N_EDGES * 8);   // stg is the larger member
    int2*  stg     = (int2*)uni;
    __half* h1h    = (__half*)uni;
    __half* rh     = h1h + (size_t)N_NODES * F_HID;

    // --- CSR build (dst-major buckets, packed 4B entries) ---
    hipMemsetAsync(bincnt, 0, (size_t)NBINS * 4, stream);
    binhist_kernel<<<1024, 256, 0, stream>>>(ei, bincnt);
    binscan_kernel<<<1, 512, 0, stream>>>(bincnt, binbase, cursor, offs);
    partA_kernel<<<(N_EDGES + EPB - 1) / EPB, 256, 0, stream>>>(ei, ew, cursor, stg);
    partB_kernel<<<NBINS, 256, 0, stream>>>(binbase, stg, offs, bkt);

    // --- Layer 1: h1 = x@W1 (fp16 table), r = relu(agg(h1)+b1) (fp16 table) ---
    gemm1_kernel<<<N_NODES / 32, 256, 0, stream>>>(x, W1, h1h);
    gather1_kernel<<<N_NODES / 4, 256, 0, stream>>>(offs, bkt, h1h, b1, rh);

    // --- Layer 2 (aggregate-then-transform) + bias2 + log-softmax, fused ---
    gather2_lsm_kernel<<<N_NODES / 4, 256, 0, stream>>>(offs, bkt, rh, W2, b2, out);
}